// Round 11
// baseline (40.282 us; speedup 1.0000x reference)
//
#include <hip/hip_runtime.h>
#include <stdint.h>

#define IMG  512
#define CPT  8
#define CGRP (IMG / CPT)    // 64 col-groups per row

typedef _Float16 h2    __attribute__((ext_vector_type(2)));
typedef __fp16   f16x2 __attribute__((ext_vector_type(2)));

static __device__ __forceinline__ h2 pkrtz(float a, float b) {
    f16x2 t = __builtin_amdgcn_cvt_pkrtz(a, b);   // v_cvt_pkrtz_f16_f32
    return __builtin_bit_cast(h2, t);
}

#if __has_builtin(__builtin_amdgcn_fdot2)
#define FDOT2(a, b, c) __builtin_amdgcn_fdot2((a), (b), (c), false)
#else
static __device__ __forceinline__ float fdot2_sw(h2 a, h2 b, float c) {
    return fmaf((float)a.x, (float)b.x, fmaf((float)a.y, (float)b.y, c));
}
#define FDOT2(a, b, c) fdot2_sw((a), (b), (c))
#endif

// tanh via 4096-entry LDS LUT on [-4,4], nearest-neighbor.
// entry i = tanh((i+0.5)/512 - 4); index = clamp(floor((x+4)*512), 0, 4095).
// err <= (1/1024)*max|tanh'| ~= 9.8e-4; for |x|>4, clamped entry err <= 6.7e-4.
// Rationale (R10 post-mortem): trans ops are ~16cy (1/8 rate) and pk_f32 is
// throughput-neutral (FP32 peak = 1 FMA/lane/cy), so NO ALU tanh beats a
// 6-8cy VALU address calc + ds_read on the otherwise-idle LDS pipe.

__global__ __launch_bounds__(256) void fused_convtap_kernel(
    const float* __restrict__ x,   // (B,1,512,512)
    const float* __restrict__ W,   // (9,1,3,3)
    const float* __restrict__ Bv,  // (9,)
    float* __restrict__ out)       // (B,1,512,512)
{
    __shared__ float lut[4096];
#pragma unroll
    for (int k = 0; k < 16; ++k) {
        const int i  = threadIdx.x + (k << 8);
        // xi = (i+0.5)/512 - 4 ; tanh(xi) = 1 - 2/(exp2(xi*2log2e)+1)
        const float xi = fmaf((float)i, 0.001953125f, 0.0009765625f - 4.0f);
        const float e  = __builtin_amdgcn_exp2f(xi * 2.8853900817779268f);
        lut[i] = 1.0f - 2.0f * __builtin_amdgcn_rcpf(e + 1.0f);
    }
    __syncthreads();

    const int tid = blockIdx.x * 256 + threadIdx.x;
    const int xg  = tid & (CGRP - 1);
    const int row = tid >> 6;            // b*IMG + y
    const int y   = row & (IMG - 1);
    const int x0  = xg * CPT;

    const float* xr = x + (size_t)row * IMG;

    // Uniform weights (s_loads); f16 pairs built per-thread.
    h2 u[9][4];
    float w8[9], bv[9];
#pragma unroll
    for (int c = 0; c < 9; ++c) {
#pragma unroll
        for (int k = 0; k < 4; ++k)
            u[c][k] = pkrtz(W[c * 9 + 2 * k], W[c * 9 + 2 * k + 1]);
        w8[c] = W[c * 9 + 8];
        bv[c] = Bv[c];
    }

    const bool has_l = (x0 > 0);
    const bool has_r = (x0 < IMG - CPT);

    // Input rows y-1, y, y+1; columns x0-1 .. x0+8 (zero-padded outside).
    float r0[10], r1[10], r2[10];
    auto load_row = [&](const float* p, float* r) {
        float4 a = *reinterpret_cast<const float4*>(p + x0);
        float4 c = *reinterpret_cast<const float4*>(p + x0 + 4);
        r[1] = a.x; r[2] = a.y; r[3] = a.z; r[4] = a.w;
        r[5] = c.x; r[6] = c.y; r[7] = c.z; r[8] = c.w;
        r[0] = has_l ? p[x0 - 1] : 0.0f;
        r[9] = has_r ? p[x0 + 8] : 0.0f;
    };
    auto zero_row = [&](float* r) {
#pragma unroll
        for (int k = 0; k < 10; ++k) r[k] = 0.0f;
    };

    if (y > 0)       load_row(xr - IMG, r0); else zero_row(r0);
                     load_row(xr,       r1);
    if (y < IMG - 1) load_row(xr + IMG, r2); else zero_row(r2);

    // tanh lookup: clamp+floor index into the block-local LUT.
    auto tlu = [&](float v) -> float {
        float t = __builtin_amdgcn_fmed3f(fmaf(v, 512.0f, 2048.0f),
                                          0.0f, 4095.0f);
        return lut[(int)t];
    };

    float o[CPT];
#pragma unroll
    for (int tp = 0; tp < 4; ++tp) {
        const int t0 = 2 * tp;
        // f16 K-pairs for pixels t0 and t0+1:
        // A=(p0q0,p0q1) B=(p0q2,p1q0) C=(p1q1,p1q2) D=(p2q0,p2q1), lone p2q2 f32
        h2 A0 = pkrtz(r0[t0],     r0[t0 + 1]);
        h2 B0 = pkrtz(r0[t0 + 2], r1[t0]);
        h2 C0 = pkrtz(r1[t0 + 1], r1[t0 + 2]);
        h2 D0 = pkrtz(r2[t0],     r2[t0 + 1]);
        h2 A1 = pkrtz(r0[t0 + 1], r0[t0 + 2]);
        h2 B1 = pkrtz(r0[t0 + 3], r1[t0 + 1]);
        h2 C1 = pkrtz(r1[t0 + 2], r1[t0 + 3]);
        h2 D1 = pkrtz(r2[t0 + 1], r2[t0 + 2]);

        float ox = 0.0f, oy = 0.0f;
#pragma unroll
        for (int c = 0; c < 9; ++c) {
            float fx = bv[c], fy = bv[c];
            fx = FDOT2(A0, u[c][0], fx);
            fy = FDOT2(A1, u[c][0], fy);
            fx = FDOT2(B0, u[c][1], fx);
            fy = FDOT2(B1, u[c][1], fy);
            fx = FDOT2(C0, u[c][2], fx);
            fy = FDOT2(C1, u[c][2], fy);
            fx = FDOT2(D0, u[c][3], fx);
            fy = FDOT2(D1, u[c][3], fy);
            fx = fmaf(r2[t0 + 2], w8[c], fx);
            fy = fmaf(r2[t0 + 3], w8[c], fy);

            const float thx = tlu(fx);
            const float thy = tlu(fy);

            // tap stage: out += patch[j][i] * tanh(fc_c), c = 3i+j
            const int i = c / 3, j = c - 3 * i;
            const float* rj = (j == 0) ? r0 : (j == 1) ? r1 : r2;
            ox = fmaf(rj[t0 + i],     thx, ox);
            oy = fmaf(rj[t0 + 1 + i], thy, oy);
        }
        o[t0] = ox; o[t0 + 1] = oy;
    }

    float* orow = out + (size_t)row * IMG + x0;
    *reinterpret_cast<float4*>(orow)     = make_float4(o[0], o[1], o[2], o[3]);
    *reinterpret_cast<float4*>(orow + 4) = make_float4(o[4], o[5], o[6], o[7]);
}

extern "C" void kernel_launch(void* const* d_in, const int* in_sizes, int n_in,
                              void* d_out, int out_size, void* d_ws, size_t ws_size,
                              hipStream_t stream) {
    const float* x  = (const float*)d_in[0];   // (B,1,512,512) f32
    const float* W  = (const float*)d_in[1];   // (9,1,3,3)     f32
    const float* Bv = (const float*)d_in[2];   // (9,)          f32
    float* out = (float*)d_out;

    const int batch   = in_sizes[0] / (IMG * IMG);   // 32
    const int threads = batch * IMG * CGRP;          // 1,048,576
    const int grid    = threads / 256;               // 4096
    fused_convtap_kernel<<<grid, 256, 0, stream>>>(x, W, Bv, out);
}

// Round 12
// 38.728 us; speedup vs baseline: 1.0401x; 1.0401x over previous
//
#include <hip/hip_runtime.h>
#include <stdint.h>

#define IMG  512
#define CPT  8
#define CGRP (IMG / CPT)    // 64 col-groups per row

// tanh via 4096-entry LDS LUT on [-4,4], nearest-neighbor.
// entry i = tanh((i+0.5)/512 - 4); index = clamp(floor((x+4)*512), 0, 4095).
// err <= 9.8e-4 in range; clamped-tail err <= 6.7e-4.
//
// Conv is SCALAR f32 FMA: the only op with a spec-guaranteed full rate
// (157.3 TF = 1 FMA/lane/cy). R5-R11 post-mortem: v_dot2_f32_f16 fits
// quarter-rate (~7.5 cy) across rounds -- the dot2 conv was the common
// element of every ~40us-pinned kernel. Trans ops fit ~20 cy -> LUT wins.

__global__ __launch_bounds__(256) void fused_convtap_kernel(
    const float* __restrict__ x,   // (B,1,512,512)
    const float* __restrict__ W,   // (9,1,3,3)
    const float* __restrict__ Bv,  // (9,)
    float* __restrict__ out)       // (B,1,512,512)
{
    __shared__ float lut[4096];
#pragma unroll
    for (int k = 0; k < 16; ++k) {
        const int i  = threadIdx.x + (k << 8);
        // xi = (i+0.5)/512 - 4 ; tanh(xi) = 1 - 2/(exp2(xi*2log2e)+1)
        const float xi = fmaf((float)i, 0.001953125f, 0.0009765625f - 4.0f);
        const float e  = __builtin_amdgcn_exp2f(xi * 2.8853900817779268f);
        lut[i] = 1.0f - 2.0f * __builtin_amdgcn_rcpf(e + 1.0f);
    }
    __syncthreads();

    const int tid = blockIdx.x * 256 + threadIdx.x;
    const int xg  = tid & (CGRP - 1);
    const int row = tid >> 6;            // b*IMG + y
    const int y   = row & (IMG - 1);
    const int x0  = xg * CPT;

    const float* xr = x + (size_t)row * IMG;

    // Uniform weights/bias -> SGPRs (s_loads); SGPR operand feeds v_fma
    // directly (1 sgpr/VALU-inst allowed).
    float w[81];
#pragma unroll
    for (int k = 0; k < 81; ++k) w[k] = W[k];
    float bv[9];
#pragma unroll
    for (int c = 0; c < 9; ++c) bv[c] = Bv[c];

    const bool has_l = (x0 > 0);
    const bool has_r = (x0 < IMG - CPT);

    // Input rows y-1, y, y+1; columns x0-1 .. x0+8 (zero-padded outside).
    float r0[10], r1[10], r2[10];
    auto load_row = [&](const float* p, float* r) {
        float4 a = *reinterpret_cast<const float4*>(p + x0);
        float4 c = *reinterpret_cast<const float4*>(p + x0 + 4);
        r[1] = a.x; r[2] = a.y; r[3] = a.z; r[4] = a.w;
        r[5] = c.x; r[6] = c.y; r[7] = c.z; r[8] = c.w;
        r[0] = has_l ? p[x0 - 1] : 0.0f;
        r[9] = has_r ? p[x0 + 8] : 0.0f;
    };
    auto zero_row = [&](float* r) {
#pragma unroll
        for (int k = 0; k < 10; ++k) r[k] = 0.0f;
    };

    if (y > 0)       load_row(xr - IMG, r0); else zero_row(r0);
                     load_row(xr,       r1);
    if (y < IMG - 1) load_row(xr + IMG, r2); else zero_row(r2);

    // tanh lookup: clamp+floor index into the block-local LUT.
    auto tlu = [&](float v) -> float {
        float t = __builtin_amdgcn_fmed3f(fmaf(v, 512.0f, 2048.0f),
                                          0.0f, 4095.0f);
        return lut[(int)t];
    };

#define RSEL(p, idx) ((p) == 0 ? r0[idx] : (p) == 1 ? r1[idx] : r2[idx])

    float o[CPT];
#pragma unroll
    for (int t = 0; t < CPT; ++t) {
        float acc = 0.0f;
#pragma unroll
        for (int i = 0; i < 3; ++i) {
#pragma unroll
            for (int j = 0; j < 3; ++j) {
                const int c = 3 * i + j;
                float fc = bv[c];
#pragma unroll
                for (int p = 0; p < 3; ++p) {
#pragma unroll
                    for (int q = 0; q < 3; ++q)
                        fc = fmaf(RSEL(p, t + q), w[c * 9 + p * 3 + q], fc);
                }
                acc = fmaf(RSEL(j, t + i), tlu(fc), acc);
            }
        }
        o[t] = acc;
    }
#undef RSEL

    float* orow = out + (size_t)row * IMG + x0;
    *reinterpret_cast<float4*>(orow)     = make_float4(o[0], o[1], o[2], o[3]);
    *reinterpret_cast<float4*>(orow + 4) = make_float4(o[4], o[5], o[6], o[7]);
}

extern "C" void kernel_launch(void* const* d_in, const int* in_sizes, int n_in,
                              void* d_out, int out_size, void* d_ws, size_t ws_size,
                              hipStream_t stream) {
    const float* x  = (const float*)d_in[0];   // (B,1,512,512) f32
    const float* W  = (const float*)d_in[1];   // (9,1,3,3)     f32
    const float* Bv = (const float*)d_in[2];   // (9,)          f32
    float* out = (float*)d_out;

    const int batch   = in_sizes[0] / (IMG * IMG);   // 32
    const int threads = batch * IMG * CGRP;          // 1,048,576
    const int grid    = threads / 256;               // 4096
    fused_convtap_kernel<<<grid, 256, 0, stream>>>(x, W, Bv, out);
}